// Round 15
// baseline (1583.771 us; speedup 1.0000x reference)
//
#include <hip/hip_runtime.h>
#include <hip/hip_bf16.h>

typedef unsigned short u16;

#define NN 4096
#define SS 1024
#define NSAMP 32
#define NGRP 16384            // 16*1024 groups
#define ROWS 524288           // NGRP*NSAMP
#define BN_EPS_F 1e-5f
#define INV_ROWS (1.0f/524288.0f)

// ---------------- zero the 512-float stats block ----------------
__global__ void zero_kernel(float* p){
    p[threadIdx.x] = 0.0f;   // launched with 512 threads
}

// ---------------- FPS v7 (660us plateau): DPP wave-reduce ----------------
// Key = (distbits<<32)|(NN-1-idx): exact argmax with first-index tie-break.
#define FPS_DPP_STEP(CTRL)                                                              \
    {   int hs = __builtin_amdgcn_update_dpp((int)(bk >> 32), (int)(bk >> 32),          \
                                             CTRL, 0xf, 0xf, false);                    \
        int ls = __builtin_amdgcn_update_dpp((int)bk, (int)bk, CTRL, 0xf, 0xf, false);  \
        unsigned long long o = ((unsigned long long)(unsigned int)hs << 32)             \
                               | (unsigned int)ls;                                      \
        bk = bk > o ? bk : o; }

__global__ __launch_bounds__(256, 1) void fps_kernel(const float* __restrict__ xyz,
                                                     float* __restrict__ out){
    __shared__ float xs[NN], ys[NN], zs[NN];
    __shared__ unsigned long long red[2][4];
    const int b = blockIdx.x;
    const int tid = threadIdx.x;
    const float* xb = xyz + (size_t)b * NN * 3;
    float px[16], py[16], pz[16], dreg[16];
    unsigned int inv[16];
    #pragma unroll
    for (int p = 0; p < 16; ++p){
        int i = tid + p * 256;
        float x = xb[i*3+0], y = xb[i*3+1], z = xb[i*3+2];
        px[p] = x; py[p] = y; pz[p] = z;
        xs[i] = x; ys[i] = y; zs[i] = z;
        dreg[p] = 1e10f;                      // ref init 1e10 (exact f32)
        inv[p] = (unsigned int)(NN - 1 - i);  // loop-invariant key low word
    }
    int cur = 0;
    __syncthreads();
    if (tid == 0){  // fps_idx[b,0] == 0 (scan emits carry before update)
        float* of = out + (size_t)b * SS * 3;
        of[0] = xs[0]; of[1] = ys[0]; of[2] = zs[0];
    }
    const int wave = tid >> 6, lane = tid & 63;
    for (int it = 1; it < SS; ++it){
        float cx = xs[cur], cy = ys[cur], cz = zs[cur];   // uniform LDS broadcast
        unsigned long long t[16];
        // strict fp32, no fma contraction: must match numpy's ((dx*dx+dy*dy)+dz*dz) bitwise
        #pragma unroll
        for (int p = 0; p < 16; ++p){
            float dx = __fsub_rn(px[p], cx);
            float dy = __fsub_rn(py[p], cy);
            float dz = __fsub_rn(pz[p], cz);
            float dd = __fadd_rn(__fadd_rn(__fmul_rn(dx,dx), __fmul_rn(dy,dy)),
                                 __fmul_rn(dz,dz));
            dreg[p] = fminf(dreg[p], dd);
            t[p] = ((unsigned long long)__float_as_uint(dreg[p]) << 32) | inv[p];
        }
        // pairwise tree (ILP) instead of serial 16-deep chain
        #pragma unroll
        for (int s = 8; s >= 1; s >>= 1)
            #pragma unroll
            for (int i2 = 0; i2 < s; ++i2)
                if (t[i2 + s] > t[i2]) t[i2] = t[i2 + s];
        unsigned long long bk = t[0];
        // DPP reduce over 64 lanes -> winner at lane 63 (VALU pipe, no DS latency)
        FPS_DPP_STEP(0x111)  // row_shr:1
        FPS_DPP_STEP(0x112)  // row_shr:2
        FPS_DPP_STEP(0x114)  // row_shr:4
        FPS_DPP_STEP(0x118)  // row_shr:8  -> lane15 of each row = row max
        FPS_DPP_STEP(0x142)  // row_bcast:15 -> lane31/63 accumulate halves
        FPS_DPP_STEP(0x143)  // row_bcast:31 -> lane63 = wave max
        unsigned int wh = (unsigned int)__builtin_amdgcn_readlane((int)(bk >> 32), 63);
        unsigned int wl = (unsigned int)__builtin_amdgcn_readlane((int)bk, 63);
        if (lane == 0) red[it & 1][wave] = ((unsigned long long)wh << 32) | wl;
        __syncthreads();                       // double-buffered red: one barrier/iter
        unsigned long long m0 = red[it & 1][0];
        #pragma unroll
        for (int w = 1; w < 4; ++w){
            unsigned long long o = red[it & 1][w];
            m0 = m0 > o ? m0 : o;
        }
        cur = (NN - 1 - (int)(m0 & 0xffffffffu)) & (NN - 1);
        if (tid == 0){
            float* of = out + ((size_t)b * SS + it) * 3;
            of[0] = xs[cur]; of[1] = ys[cur]; of[2] = zs[cur];
        }
    }
}

// ---------------- ball query v3: 512-pt super-chunks, pipelined masks ----------------
__global__ __launch_bounds__(256) void ballq_kernel(const float* __restrict__ xyz,
                                                    const float* __restrict__ outc,
                                                    u16* __restrict__ gidx){
    const int g = (blockIdx.x << 2) + (threadIdx.x >> 6);
    const int lane = threadIdx.x & 63;
    const int b = g >> 10;
    const float rr = 0.04f;   // np.float32 promotion of python 0.2*0.2
    const float* c = outc + (size_t)g * 3;
    float cx = c[0], cy = c[1], cz = c[2];
    float sa = __fadd_rn(__fadd_rn(__fmul_rn(cx,cx), __fmul_rn(cy,cy)), __fmul_rn(cz,cz));
    const float* xb = xyz + (size_t)b * NN * 3;
    u16* outp = gidx + (size_t)g * NSAMP;
    int count = 0, first = -1;
    const unsigned long long below = (1ull << lane) - 1ull;
    for (int base = 0; base < NN && count < NSAMP; base += 512){
        unsigned long long masks[8];
        #pragma unroll
        for (int u = 0; u < 8; ++u){          // 8 independent distance+ballot: loads pipeline
            int n = base + u * 64 + lane;
            float x = xb[n*3+0], y = xb[n*3+1], z = xb[n*3+2];
            // reference: sum(a^2) - 2*dot + sum(b^2), fp32, no contraction
            float sb = __fadd_rn(__fadd_rn(__fmul_rn(x,x), __fmul_rn(y,y)), __fmul_rn(z,z));
            float dt = __fadd_rn(__fadd_rn(__fmul_rn(cx,x), __fmul_rn(cy,y)), __fmul_rn(cz,z));
            float sq = __fadd_rn(__fsub_rn(sa, __fmul_rn(2.0f, dt)), sb);
            masks[u] = __ballot(!(sq > rr));
        }
        #pragma unroll
        for (int u = 0; u < 8; ++u){          // append phase: VALU-only serial chain
            unsigned long long m = masks[u];
            bool w = (m >> lane) & 1ull;
            int pos = __popcll(m & below);
            if (w && (count + pos) < NSAMP) outp[count + pos] = (u16)(base + u * 64 + lane);
            if (first < 0 && m != 0ull) first = base + u * 64 + (__ffsll((long long)m) - 1);
            count += __popcll(m);
        }
    }
    for (int j = count + lane; j < NSAMP; j += 64) outp[j] = (u16)first;
}

// ---------------- shared helpers ----------------
__device__ __forceinline__ void gather_row(const float* __restrict__ xyz, const float* __restrict__ pts,
                                           const float* __restrict__ outc, const u16* __restrict__ gidx,
                                           int row, float* x){
    int g = row >> 5;
    int b = row >> 15;
    int i = gidx[row];
    const float* cc = outc + (size_t)g * 3;
    const float* xp = xyz + ((size_t)b * NN + i) * 3;
    const float* pp = pts + ((size_t)b * NN + i) * 6;
    x[0] = __fsub_rn(xp[0], cc[0]);
    x[1] = __fsub_rn(xp[1], cc[1]);
    x[2] = __fsub_rn(xp[2], cc[2]);
    #pragma unroll
    for (int k = 0; k < 6; ++k) x[3+k] = pp[k];
}

__device__ __forceinline__ void bn_coef(const float* sums, const float* ssqs,
                                        const float* g, const float* bbv, int ch,
                                        float* sc, float* sh){
    float mu = sums[ch] * INV_ROWS;
    float var = fmaf(-mu, mu, ssqs[ch] * INV_ROWS);
    var = fmaxf(var, 0.0f);
    float is = rsqrtf(var + BN_EPS_F);
    float s = is * g[ch];
    sc[ch] = s;
    sh[ch] = fmaf(-mu, s, bbv[ch]);
}

// 8-way-split dot of length 64 (chain 8 deep instead of 16)
__device__ __forceinline__ float dot64_8(const float* __restrict__ v, const float* __restrict__ w, float bias){
    float a0 = bias, a1 = 0.f, a2 = 0.f, a3 = 0.f, a4 = 0.f, a5 = 0.f, a6 = 0.f, a7 = 0.f;
    #pragma unroll
    for (int k = 0; k < 64; k += 8){
        a0 = fmaf(v[k+0], w[k+0], a0);
        a1 = fmaf(v[k+1], w[k+1], a1);
        a2 = fmaf(v[k+2], w[k+2], a2);
        a3 = fmaf(v[k+3], w[k+3], a3);
        a4 = fmaf(v[k+4], w[k+4], a4);
        a5 = fmaf(v[k+5], w[k+5], a5);
        a6 = fmaf(v[k+6], w[k+6], a6);
        a7 = fmaf(v[k+7], w[k+7], a7);
    }
    return ((a0+a1)+(a2+a3)) + ((a4+a5)+(a6+a7));
}

// ---------------- stats1 v3: 32-ch chunks, tr[256][33] (~37KB LDS -> 4 blocks/CU) ----------------
__global__ __launch_bounds__(256, 4) void stats1_kernel(const float* __restrict__ xyz, const float* __restrict__ pts,
                                                        const float* __restrict__ outc, const u16* __restrict__ gidx,
                                                        const float* __restrict__ W0f, const float* __restrict__ b0f,
                                                        float* __restrict__ stats){
    __shared__ float tr[256 * 33];
    __shared__ float accs[8][32], accq[8][32];
    const int row = blockIdx.x * 256 + threadIdx.x;
    float x[9];
    gather_row(xyz, pts, outc, gidx, row, x);
    const int e = threadIdx.x >> 5, ch5 = threadIdx.x & 31;
    for (int chunk = 0; chunk < 2; ++chunk){
        #pragma unroll
        for (int c32 = 0; c32 < 32; ++c32){
            int j = chunk * 32 + c32;
            float acc = b0f[j];
            #pragma unroll
            for (int k = 0; k < 9; ++k) acc = fmaf(x[k], W0f[j*9+k], acc);
            tr[threadIdx.x * 33 + c32] = acc;
        }
        __syncthreads();
        float s = 0.f, q = 0.f;
        for (int r = 0; r < 32; ++r){
            float v = tr[(e * 32 + r) * 33 + ch5];
            s += v; q = fmaf(v, v, q);
        }
        accs[e][ch5] = s; accq[e][ch5] = q;
        __syncthreads();
        if (threadIdx.x < 32){
            int c = threadIdx.x;
            float t = ((accs[0][c]+accs[1][c])+(accs[2][c]+accs[3][c]))
                    + ((accs[4][c]+accs[5][c])+(accs[6][c]+accs[7][c]));
            atomicAdd(&stats[chunk * 32 + c], t);
        } else if (threadIdx.x < 64){
            int c = threadIdx.x - 32;
            float t = ((accq[0][c]+accq[1][c])+(accq[2][c]+accq[3][c]))
                    + ((accq[4][c]+accq[5][c])+(accq[6][c]+accq[7][c]));
            atomicAdd(&stats[64 + chunk * 32 + c], t);
        }
        // next chunk's tr writes are safe after the accs barrier (reduce reads done);
        // accs rewrite is protected by the next chunk's first barrier (program order).
    }
}

// ---------------- stats2 v6: 32-ch chunks + 8-acc dots, (256,4) ----------------
__global__ __launch_bounds__(256, 4) void stats2_kernel(const float* __restrict__ xyz, const float* __restrict__ pts,
                                                        const float* __restrict__ outc, const u16* __restrict__ gidx,
                                                        const float* __restrict__ W0f, const float* __restrict__ b0f,
                                                        const float* __restrict__ W1f, const float* __restrict__ b1f,
                                                        const float* __restrict__ g0, const float* __restrict__ bb0,
                                                        float* __restrict__ stats){
    __shared__ float sc1[64], sh1[64];
    __shared__ float tr[256 * 33];
    __shared__ float accs[8][32], accq[8][32];
    if (threadIdx.x < 64) bn_coef(stats + 0, stats + 64, g0, bb0, threadIdx.x, sc1, sh1);
    __syncthreads();
    const int row = blockIdx.x * 256 + threadIdx.x;
    float x[9];
    gather_row(xyz, pts, outc, gidx, row, x);
    float x2[64];
    #pragma unroll
    for (int j = 0; j < 64; ++j){
        float acc = b0f[j];
        #pragma unroll
        for (int k = 0; k < 9; ++k) acc = fmaf(x[k], W0f[j*9+k], acc);
        x2[j] = fmaxf(fmaf(acc, sc1[j], sh1[j]), 0.f);
    }
    const int e = threadIdx.x >> 5, ch5 = threadIdx.x & 31;
    for (int chunk = 0; chunk < 2; ++chunk){
        for (int c32 = 0; c32 < 32; ++c32){
            int ch = chunk * 32 + c32;
            tr[threadIdx.x * 33 + c32] = dot64_8(x2, W1f + ch * 64, b1f[ch]);
        }
        __syncthreads();
        float s = 0.f, q = 0.f;
        for (int r = 0; r < 32; ++r){
            float v = tr[(e * 32 + r) * 33 + ch5];
            s += v; q = fmaf(v, v, q);
        }
        accs[e][ch5] = s; accq[e][ch5] = q;
        __syncthreads();
        if (threadIdx.x < 32){
            int c = threadIdx.x;
            float t = ((accs[0][c]+accs[1][c])+(accs[2][c]+accs[3][c]))
                    + ((accs[4][c]+accs[5][c])+(accs[6][c]+accs[7][c]));
            atomicAdd(&stats[128 + chunk * 32 + c], t);
        } else if (threadIdx.x < 64){
            int c = threadIdx.x - 32;
            float t = ((accq[0][c]+accq[1][c])+(accq[2][c]+accq[3][c]))
                    + ((accq[4][c]+accq[5][c])+(accq[6][c]+accq[7][c]));
            atomicAdd(&stats[192 + chunk * 32 + c], t);
        }
    }
}

// ---------------- stats3 v6: 4x32-ch chunks + 8-acc dots; pmax/pmin per eighth(=group) ----------------
__global__ __launch_bounds__(256, 2) void stats3_kernel(const float* __restrict__ xyz, const float* __restrict__ pts,
                                                        const float* __restrict__ outc, const u16* __restrict__ gidx,
                                                        const float* __restrict__ W0f, const float* __restrict__ b0f,
                                                        const float* __restrict__ W1f, const float* __restrict__ b1f,
                                                        const float* __restrict__ W2f, const float* __restrict__ b2f,
                                                        const float* __restrict__ g0, const float* __restrict__ bb0,
                                                        const float* __restrict__ g1, const float* __restrict__ bb1,
                                                        float* __restrict__ stats,
                                                        float* __restrict__ pmax, float* __restrict__ pmin){
    __shared__ float sc1[64], sh1[64], sc2[64], sh2[64];
    __shared__ float tr[256 * 33];
    __shared__ float accs[8][32], accq[8][32];
    if (threadIdx.x < 64){
        bn_coef(stats + 0,   stats + 64,  g0, bb0, threadIdx.x, sc1, sh1);
        bn_coef(stats + 128, stats + 192, g1, bb1, threadIdx.x, sc2, sh2);
    }
    __syncthreads();
    const int row = blockIdx.x * 256 + threadIdx.x;
    float x[9];
    gather_row(xyz, pts, outc, gidx, row, x);
    float x2[64];
    #pragma unroll
    for (int j = 0; j < 64; ++j){
        float acc = b0f[j];
        #pragma unroll
        for (int k = 0; k < 9; ++k) acc = fmaf(x[k], W0f[j*9+k], acc);
        x2[j] = fmaxf(fmaf(acc, sc1[j], sh1[j]), 0.f);
    }
    float x3[64];
    #pragma unroll
    for (int j = 0; j < 64; ++j){
        float d = dot64_8(x2, W1f + j * 64, b1f[j]);
        x3[j] = fmaxf(fmaf(d, sc2[j], sh2[j]), 0.f);
    }
    const int e = threadIdx.x >> 5, ch5 = threadIdx.x & 31;
    const int gbase = blockIdx.x * 8 + e;   // eighth e == group gbase (32 rows/group)
    for (int chunk = 0; chunk < 4; ++chunk){
        for (int c32 = 0; c32 < 32; ++c32){
            int ch = chunk * 32 + c32;
            tr[threadIdx.x * 33 + c32] = dot64_8(x3, W2f + ch * 64, b2f[ch]);
        }
        __syncthreads();
        float s = 0.f, q = 0.f, mx = -1e30f, mn = 1e30f;
        for (int r = 0; r < 32; ++r){
            float v = tr[(e * 32 + r) * 33 + ch5];
            s += v; q = fmaf(v, v, q);
            mx = fmaxf(mx, v); mn = fminf(mn, v);
        }
        int c = chunk * 32 + ch5;
        pmax[(size_t)gbase * 128 + c] = mx;
        pmin[(size_t)gbase * 128 + c] = mn;
        accs[e][ch5] = s; accq[e][ch5] = q;
        __syncthreads();
        if (threadIdx.x < 32){
            int cc = threadIdx.x;
            float t = ((accs[0][cc]+accs[1][cc])+(accs[2][cc]+accs[3][cc]))
                    + ((accs[4][cc]+accs[5][cc])+(accs[6][cc]+accs[7][cc]));
            atomicAdd(&stats[256 + chunk * 32 + cc], t);
        } else if (threadIdx.x < 64){
            int cc = threadIdx.x - 32;
            float t = ((accq[0][cc]+accq[1][cc])+(accq[2][cc]+accq[3][cc]))
                    + ((accq[4][cc]+accq[5][cc])+(accq[6][cc]+accq[7][cc]));
            atomicAdd(&stats[384 + chunk * 32 + cc], t);
        }
    }
}

// ---------------- BN3 applied to group max/min, relu, write out region 1 (f32) ----------------
__global__ __launch_bounds__(256) void pool_kernel(const float* __restrict__ stats,
                                                   const float* __restrict__ g2, const float* __restrict__ bb2,
                                                   const float* __restrict__ pmax, const float* __restrict__ pmin,
                                                   float* __restrict__ out){
    __shared__ float sc[128], sh[128];
    if (threadIdx.x < 128) bn_coef(stats + 256, stats + 384, g2, bb2, threadIdx.x, sc, sh);
    __syncthreads();
    int o = blockIdx.x * 256 + threadIdx.x;   // o = g*128 + ch, o < NGRP*128
    int ch = o & 127;
    float a = fmaf(pmax[o], sc[ch], sh[ch]);
    float b = fmaf(pmin[o], sc[ch], sh[ch]);  // affine maps interval endpoints (sc<0 covered)
    out[NGRP * 3 + o] = fmaxf(fmaxf(a, b), 0.0f);
}

extern "C" void kernel_launch(void* const* d_in, const int* in_sizes, int n_in,
                              void* d_out, int out_size, void* d_ws, size_t ws_size,
                              hipStream_t stream){
    const float* xyz = (const float*)d_in[0];
    const float* pts = (const float*)d_in[1];
    const float* W0  = (const float*)d_in[2];
    const float* b0  = (const float*)d_in[3];
    const float* g0  = (const float*)d_in[4];
    const float* bb0 = (const float*)d_in[5];
    const float* W1  = (const float*)d_in[6];
    const float* b1  = (const float*)d_in[7];
    const float* g1  = (const float*)d_in[8];
    const float* bb1 = (const float*)d_in[9];
    const float* W2  = (const float*)d_in[10];
    const float* b2  = (const float*)d_in[11];
    const float* g2  = (const float*)d_in[12];
    const float* bb2 = (const float*)d_in[13];
    float* out = (float*)d_out;   // f32 outputs: [new_xyz 49152 | new_points 2097152]

    // ws layout (bytes): stats[512f]@0 | gidx[524288 u16]@2048 |
    //                    pmax[2097152f]@1050624 | pmin@9439232 ; total 17,827,840
    if (ws_size < 17827840u) return;
    char*  ws    = (char*)d_ws;
    float* stats = (float*)ws;
    u16*   gidx  = (u16*)  (ws + 2048);
    float* pmax  = (float*)(ws + 1050624);
    float* pmin  = (float*)(ws + 9439232);

    zero_kernel <<<1, 512, 0, stream>>>(stats);
    fps_kernel  <<<16, 256, 0, stream>>>(xyz, out);
    ballq_kernel<<<NGRP/4, 256, 0, stream>>>(xyz, out, gidx);
    stats1_kernel<<<ROWS/256, 256, 0, stream>>>(xyz, pts, out, gidx, W0, b0, stats);
    stats2_kernel<<<ROWS/256, 256, 0, stream>>>(xyz, pts, out, gidx, W0, b0, W1, b1, g0, bb0, stats);
    stats3_kernel<<<ROWS/256, 256, 0, stream>>>(xyz, pts, out, gidx, W0, b0, W1, b1, W2, b2,
                                                g0, bb0, g1, bb1, stats, pmax, pmin);
    pool_kernel <<<NGRP*128/256, 256, 0, stream>>>(stats, g2, bb2, pmax, pmin, out);
}